// Round 5
// baseline (578.666 us; speedup 1.0000x reference)
//
#include <hip/hip_runtime.h>
#include <hip/hip_bf16.h>

// ---- problem constants ----
#define NW 5
#define KS 5
#define SEQ 196
#define DIM 384
#define NSUP 25        // NW*KS support images
#define NQRY 75        // query images
#define NIMG 100       // NSUP + NQRY
#define LSUP 4900      // NSUP*SEQ support rows
#define BLOCK_W 980    // KS*SEQ rows per class block
#define PADW 1024      // padded class block for opt kernel
#define OPT_STEPS 15

static constexpr float TEMP_F = 0.0510310363f;
static constexpr float INV_T  = 1.0f / TEMP_F;   // ~19.5959
static constexpr float LR_F   = 0.1f;

typedef short v8s __attribute__((ext_vector_type(8)));   // 8 x bf16 frag (4 VGPRs)
typedef float v4f __attribute__((ext_vector_type(4)));   // 4 x f32 acc

__device__ inline unsigned short f2bf(float x) {
    unsigned int u = __float_as_uint(x);
    u += 0x7fffu + ((u >> 16) & 1u);
    return (unsigned short)(u >> 16);
}
__device__ inline float bf2f(unsigned int u) {
    return __uint_as_float(u << 16);
}
__device__ inline void unpack8(uint4 u, float* f) {
    f[0] = bf2f(u.x & 0xffffu); f[1] = bf2f(u.x >> 16);
    f[2] = bf2f(u.y & 0xffffu); f[3] = bf2f(u.y >> 16);
    f[4] = bf2f(u.z & 0xffffu); f[5] = bf2f(u.z >> 16);
    f[6] = bf2f(u.w & 0xffffu); f[7] = bf2f(u.w >> 16);
}

// ---------------------------------------------------------------------------
// Kernel 1: fused normalize of all 24500 rows -> bf16. One wave per row.
// rows [0,4900): sup_key -> Kb (pre-scaled by 1/T)
// rows [4900,9800): sup_qry -> Qall[0..4899]
// rows [9800,24500): qry -> Qall[4900..19599]
// ---------------------------------------------------------------------------
__global__ __launch_bounds__(256) void norm_all(const float* __restrict__ sup_key,
                                                const float* __restrict__ sup_qry,
                                                const float* __restrict__ qry,
                                                unsigned short* __restrict__ Kb,
                                                unsigned short* __restrict__ Qall) {
    int row = blockIdx.x * 4 + (threadIdx.x >> 6);
    int lane = threadIdx.x & 63;
    if (row >= 2 * LSUP + NQRY * SEQ) return;
    const float* src;
    unsigned short* dst;
    float scale;
    if (row < LSUP) {
        src = sup_key + (size_t)row * DIM;
        dst = Kb + (size_t)row * DIM;
        scale = INV_T;
    } else if (row < 2 * LSUP) {
        src = sup_qry + (size_t)(row - LSUP) * DIM;
        dst = Qall + (size_t)(row - LSUP) * DIM;
        scale = 1.0f;
    } else {
        src = qry + (size_t)(row - 2 * LSUP) * DIM;
        dst = Qall + (size_t)(row - LSUP) * DIM;
        scale = 1.0f;
    }
    float x[6];
    float s = 0.f;
    #pragma unroll
    for (int i = 0; i < 6; ++i) { x[i] = src[lane + 64 * i]; s += x[i] * x[i]; }
    #pragma unroll
    for (int m = 1; m < 64; m <<= 1) s += __shfl_xor(s, m);
    float sc = scale / fmaxf(sqrtf(s), 1e-8f);
    #pragma unroll
    for (int i = 0; i < 6; ++i) dst[lane + 64 * i] = f2bf(x[i] * sc);
}

// ---------------------------------------------------------------------------
// Kernel 2: MFMA fused exp-sum GEMM, A-in-registers / full-image-B-in-LDS.
//   R[img][r] = sum_qs exp( (Kn[r] . Qimg[qs]) / T )    (K pre-scaled by 1/T)
// Block: 512 thr = 8 waves, each wave owns 48 rows (3 m-tiles), full K=384
// held in registers (36 v8s frags -> 144 VGPRs; ALL indexing constant so the
// array stays in registers). B staged in 3 col-passes of 80 qs.
// img<25 -> write bf16 to Rbf[b][w*1024+r] (masked rows -> 0)
// img>=25 -> write f32 to Rq[(img-25)*4900 + r]
// ---------------------------------------------------------------------------
#define QTILE 80
#define LDB   392   // LDS row stride in shorts (384+8): 16B aligned

__global__ __launch_bounds__(512, 2) void fused_gemm(
    const unsigned short* __restrict__ Kb,
    const unsigned short* __restrict__ Qall,
    float* __restrict__ Rq,
    unsigned short* __restrict__ Rbf)
{
    __shared__ __align__(16) unsigned short Bs[QTILE * LDB];  // 62720 B

    int t = threadIdx.x;
    int img = blockIdx.y;
    int wv = t >> 6, l = t & 63;
    int lo = l & 15, hi = l >> 4;
    const unsigned short* Q = Qall + (size_t)img * SEQ * DIM;
    int row0 = blockIdx.x * 384 + wv * 48;

    // --- load A fragments: 3 m-tiles x 12 k-tiles, once, from L2 ---
    v8s A[3][12];
    #pragma unroll
    for (int mm = 0; mm < 3; ++mm) {
        #pragma unroll
        for (int kk = 0; kk < 12; ++kk) {
            int gr = row0 + mm * 16 + lo;
            v8s z = {0, 0, 0, 0, 0, 0, 0, 0};
            A[mm][kk] = (gr < LSUP)
                ? *(const v8s*)(Kb + (size_t)gr * DIM + kk * 32 + hi * 8)
                : z;
        }
    }

    float srow[3][4];
    #pragma unroll
    for (int mm = 0; mm < 3; ++mm)
        #pragma unroll
        for (int j = 0; j < 4; ++j) srow[mm][j] = 0.f;

    for (int pass = 0; pass < 3; ++pass) {
        int qbase = pass * QTILE;
        int ntiles = (pass < 2) ? 5 : 3;
        int nstage = (pass < 2) ? QTILE : 48;
        // stage B tile
        for (int i = t; i < nstage * 48; i += 512) {
            int qs = i / 48, kc = i % 48;
            int gq = qbase + qs;
            float4 vv = make_float4(0.f, 0.f, 0.f, 0.f);
            if (gq < SEQ) vv = *(const float4*)(Q + (size_t)gq * DIM + kc * 8);
            *(float4*)(Bs + qs * LDB + kc * 8) = vv;
        }
        __syncthreads();

        for (int n = 0; n < ntiles; ++n) {
            v4f acc[3];
            #pragma unroll
            for (int mm = 0; mm < 3; ++mm) acc[mm] = (v4f){0.f, 0.f, 0.f, 0.f};
            const unsigned short* Bn = Bs + (n * 16 + lo) * LDB + hi * 8;
            #pragma unroll
            for (int kk = 0; kk < 12; ++kk) {       // FULL unroll: constant idx
                v8s bb = *(const v8s*)(Bn + kk * 32);
                acc[0] = __builtin_amdgcn_mfma_f32_16x16x32_bf16(A[0][kk], bb, acc[0], 0, 0, 0);
                acc[1] = __builtin_amdgcn_mfma_f32_16x16x32_bf16(A[1][kk], bb, acc[1], 0, 0, 0);
                acc[2] = __builtin_amdgcn_mfma_f32_16x16x32_bf16(A[2][kk], bb, acc[2], 0, 0, 0);
            }
            bool ok = (qbase + n * 16 + lo) < SEQ;
            #pragma unroll
            for (int mm = 0; mm < 3; ++mm)
                #pragma unroll
                for (int j = 0; j < 4; ++j)
                    srow[mm][j] += ok ? __expf(acc[mm][j]) : 0.f;
        }
        __syncthreads();
    }

    // reduce across the 16 column lanes (lo); C/D layout: col=lo, row=hi*4+j
    #pragma unroll
    for (int m = 1; m < 16; m <<= 1)
        #pragma unroll
        for (int mm = 0; mm < 3; ++mm)
            #pragma unroll
            for (int j = 0; j < 4; ++j)
                srow[mm][j] += __shfl_xor(srow[mm][j], m);

    if (lo == 0) {
        #pragma unroll
        for (int mm = 0; mm < 3; ++mm) {
            #pragma unroll
            for (int j = 0; j < 4; ++j) {
                int r = row0 + mm * 16 + hi * 4 + j;
                if (r < LSUP) {
                    float val = srow[mm][j];
                    if (img < NSUP) {
                        if (r / SEQ == img) val = 0.f;        // block-diag mask
                        int w = r / BLOCK_W, rr = r - w * BLOCK_W;
                        Rbf[(size_t)img * (NW * PADW) + w * PADW + rr] = f2bf(val);
                    } else {
                        Rq[(size_t)(img - NSUP) * LSUP + r] = val;
                    }
                }
            }
        }
    }
}

// ---------------------------------------------------------------------------
// Kernel 3: whole 15-step SGD in ONE 640-thread block, R HELD IN REGISTERS.
// Thread t owns 8 consecutive rows of class w=t>>7 (r0=(t&127)*8); its 25
// R-slices (one per support image) are 25 packed uint4 = 100 VGPRs, loaded
// once (pads r>=980 masked in-register; Rbf pads are never read as data).
// Per step:  cf from D;  g = sum_b cf[b][w]*R[b];  v -= LR*e*g; e = exp(v/T);
//            D[b][w] = sum e*R  (6-shfl butterfly per b, 2 waves per class).
// Zero global traffic inside the step loop -> pure VALU on one CU.
// ---------------------------------------------------------------------------
__global__ __launch_bounds__(640, 3) void opt_all(const unsigned short* __restrict__ Rbf,
                                                  const int* __restrict__ labels,
                                                  float* __restrict__ v_out) {
    __shared__ float D_s[128];
    __shared__ float cf_s[128];
    __shared__ float red[10][26];
    __shared__ int lab_s[NSUP];

    int t = threadIdx.x;
    int wave = t >> 6, lane = t & 63;
    int w  = t >> 7;            // class (uniform per wave)
    int r0 = (t & 127) * 8;

    if (t < NSUP) lab_s[t] = labels[t];

    // load all 25 R-slices into registers, masking pad rows (>= 980)
    uint4 R[NSUP];
    #pragma unroll
    for (int b = 0; b < NSUP; ++b) {
        uint4 u = *(const uint4*)(Rbf + (size_t)b * (NW * PADW) + w * PADW + r0);
        if (r0 >= BLOCK_W) { u.x = 0; u.y = 0; u.z = 0; u.w = 0; }
        else if (r0 + 4 >= BLOCK_W) { u.z = 0; u.w = 0; }   // boundary at 980 = r0+4
        R[b] = u;
    }

    float v8[8], e8[8];
    #pragma unroll
    for (int j = 0; j < 8; ++j) { v8[j] = 0.f; e8[j] = 1.f; }
    __syncthreads();   // lab_s visible

    // D pass: D[b][w] = sum_r e*R, butterfly within wave, combine 2 waves.
    auto dpass = [&]() {
        #pragma unroll
        for (int b = 0; b < NSUP; ++b) {
            float f[8]; unpack8(R[b], f);
            float s = 0.f;
            #pragma unroll
            for (int j = 0; j < 8; ++j) s += e8[j] * f[j];
            #pragma unroll
            for (int m = 1; m < 64; m <<= 1) s += __shfl_xor(s, m);
            if (lane == 0) red[wave][b] = s;
        }
        __syncthreads();
        if (t < 125) {
            int b = t / 5, ww = t % 5;
            D_s[t] = red[2 * ww][b] + red[2 * ww + 1][b];
        }
        __syncthreads();
    };

    dpass();    // D_0 (e = 1)

    for (int step = 0; step < OPT_STEPS; ++step) {
        if (t < 125) {
            int b = t / 5, ww = t % 5;
            float Dsum = D_s[b * 5 + 0] + D_s[b * 5 + 1] + D_s[b * 5 + 2]
                       + D_s[b * 5 + 3] + D_s[b * 5 + 4];
            float Dv = D_s[t];
            cf_s[t] = ((Dv / Dsum) - (ww == lab_s[b] ? 1.f : 0.f)) * (INV_T / 25.f) / Dv;
        }
        __syncthreads();

        float g[8];
        #pragma unroll
        for (int j = 0; j < 8; ++j) g[j] = 0.f;
        #pragma unroll
        for (int b = 0; b < NSUP; ++b) {
            float f[8]; unpack8(R[b], f);
            float c = cf_s[b * 5 + w];
            #pragma unroll
            for (int j = 0; j < 8; ++j) g[j] += c * f[j];
        }
        #pragma unroll
        for (int j = 0; j < 8; ++j) {
            v8[j] -= LR_F * e8[j] * g[j];
            e8[j] = __expf(v8[j] * INV_T);
        }
        __syncthreads();

        if (step < OPT_STEPS - 1) dpass();
    }

    #pragma unroll
    for (int j = 0; j < 8; ++j)
        if (r0 + j < BLOCK_W) v_out[w * BLOCK_W + r0 + j] = v8[j];
}

// ---------------------------------------------------------------------------
// Kernel 4: out[qb][w] = log( sum_{r in w} e^{v/T} * Rq[qb][w*980+r] )
// ---------------------------------------------------------------------------
__global__ __launch_bounds__(256) void final_pred(const float* __restrict__ Rq,
                                                  const float* __restrict__ v,
                                                  float* __restrict__ out) {
    __shared__ float wsum[4];
    int blk = blockIdx.x;           // qb*5 + w
    int qb = blk / 5, w = blk % 5;
    const float* R  = Rq + (size_t)qb * LSUP + w * BLOCK_W;
    const float* vb = v + w * BLOCK_W;
    int t = threadIdx.x;
    float p = 0.f;
    for (int i = t; i < BLOCK_W; i += 256) p += __expf(vb[i] * INV_T) * R[i];
    #pragma unroll
    for (int off = 32; off; off >>= 1) p += __shfl_down(p, off);
    if ((t & 63) == 0) wsum[t >> 6] = p;
    __syncthreads();
    if (t == 0) out[blk] = logf(wsum[0] + wsum[1] + wsum[2] + wsum[3]);
}

// ---------------------------------------------------------------------------
extern "C" void kernel_launch(void* const* d_in, const int* in_sizes, int n_in,
                              void* d_out, int out_size, void* d_ws, size_t ws_size,
                              hipStream_t stream) {
    const float* sup_key = (const float*)d_in[0];   // [25,196,384]
    const float* sup_qry = (const float*)d_in[1];   // [25,196,384]
    const float* qry     = (const float*)d_in[2];   // [75,196,384]
    const int*   labels  = (const int*)d_in[3];     // [25]
    float* out = (float*)d_out;                     // [75,5]

    char* ws = (char*)d_ws;
    size_t off = 0;
    auto take = [&](size_t bytes) {
        char* p = ws + off;
        off = (off + bytes + 255) & ~(size_t)255;
        return p;
    };
    unsigned short* Kb   = (unsigned short*)take((size_t)LSUP * DIM * 2);
    unsigned short* Qall = (unsigned short*)take((size_t)NIMG * SEQ * DIM * 2);
    float*          Rq   = (float*)take((size_t)NQRY * LSUP * 4);
    unsigned short* Rbf  = (unsigned short*)take((size_t)NSUP * NW * PADW * 2);
    float*          v    = (float*)take((size_t)LSUP * 4);

    int nrows = 2 * LSUP + NQRY * SEQ;              // 24500
    norm_all<<<(nrows + 3) / 4, 256, 0, stream>>>(sup_key, sup_qry, qry, Kb, Qall);

    fused_gemm<<<dim3(13, NIMG), 512, 0, stream>>>(Kb, Qall, Rq, Rbf);

    opt_all<<<1, 640, 0, stream>>>(Rbf, labels, v);

    final_pred<<<NQRY * NW, 256, 0, stream>>>(Rq, v, out);
}

// Round 6
// 547.101 us; speedup vs baseline: 1.0577x; 1.0577x over previous
//
#include <hip/hip_runtime.h>
#include <hip/hip_bf16.h>

// ---- problem constants ----
#define NW 5
#define KS 5
#define SEQ 196
#define DIM 384
#define NSUP 25        // NW*KS support images
#define NQRY 75        // query images
#define NIMG 100       // NSUP + NQRY
#define LSUP 4900      // NSUP*SEQ support rows
#define BLOCK_W 980    // KS*SEQ rows per class block
#define PADW 1024      // padded class block for opt kernel
#define OPT_STEPS 15

static constexpr float TEMP_F = 0.0510310363f;
static constexpr float INV_T  = 1.0f / TEMP_F;   // ~19.5959
static constexpr float LR_F   = 0.1f;

typedef short v8s __attribute__((ext_vector_type(8)));   // 8 x bf16 frag (4 VGPRs)
typedef float v4f __attribute__((ext_vector_type(4)));   // 4 x f32 acc

__device__ inline unsigned short f2bf(float x) {
    unsigned int u = __float_as_uint(x);
    u += 0x7fffu + ((u >> 16) & 1u);
    return (unsigned short)(u >> 16);
}
__device__ inline float bf2f(unsigned int u) {
    return __uint_as_float(u << 16);
}

// ---------------------------------------------------------------------------
// Kernel 1: fused normalize of all 24500 rows -> bf16. One wave per row.
// rows [0,4900): sup_key -> Kb (pre-scaled by 1/T)
// rows [4900,9800): sup_qry -> Qall[0..4899]
// rows [9800,24500): qry -> Qall[4900..19599]
// ---------------------------------------------------------------------------
__global__ __launch_bounds__(256) void norm_all(const float* __restrict__ sup_key,
                                                const float* __restrict__ sup_qry,
                                                const float* __restrict__ qry,
                                                unsigned short* __restrict__ Kb,
                                                unsigned short* __restrict__ Qall) {
    int row = blockIdx.x * 4 + (threadIdx.x >> 6);
    int lane = threadIdx.x & 63;
    if (row >= 2 * LSUP + NQRY * SEQ) return;
    const float* src;
    unsigned short* dst;
    float scale;
    if (row < LSUP) {
        src = sup_key + (size_t)row * DIM;
        dst = Kb + (size_t)row * DIM;
        scale = INV_T;
    } else if (row < 2 * LSUP) {
        src = sup_qry + (size_t)(row - LSUP) * DIM;
        dst = Qall + (size_t)(row - LSUP) * DIM;
        scale = 1.0f;
    } else {
        src = qry + (size_t)(row - 2 * LSUP) * DIM;
        dst = Qall + (size_t)(row - LSUP) * DIM;
        scale = 1.0f;
    }
    float x[6];
    float s = 0.f;
    #pragma unroll
    for (int i = 0; i < 6; ++i) { x[i] = src[lane + 64 * i]; s += x[i] * x[i]; }
    #pragma unroll
    for (int m = 1; m < 64; m <<= 1) s += __shfl_xor(s, m);
    float sc = scale / fmaxf(sqrtf(s), 1e-8f);
    #pragma unroll
    for (int i = 0; i < 6; ++i) dst[lane + 64 * i] = f2bf(x[i] * sc);
}

// ---------------------------------------------------------------------------
// Kernel 2: MFMA fused exp-sum GEMM, A-in-registers / full-image-B-in-LDS.
//   R[img][r] = sum_qs exp( (Kn[r] . Qimg[qs]) / T )    (K pre-scaled by 1/T)
// Block: 512 thr = 8 waves, each wave owns 48 rows (3 m-tiles), full K=384
// held in registers (36 v8s frags -> 144 VGPRs; ALL indexing constant so the
// array stays in registers). B staged in 3 col-passes of 80 qs.
// img<25 -> write bf16 to Rbf[b][w*1024+r] (masked rows -> 0)
// img>=25 -> write f32 to Rq[(img-25)*4900 + r]
// ---------------------------------------------------------------------------
#define QTILE 80
#define LDB   392   // LDS row stride in shorts (384+8): 16B aligned

__global__ __launch_bounds__(512, 2) void fused_gemm(
    const unsigned short* __restrict__ Kb,
    const unsigned short* __restrict__ Qall,
    float* __restrict__ Rq,
    unsigned short* __restrict__ Rbf)
{
    __shared__ __align__(16) unsigned short Bs[QTILE * LDB];  // 62720 B

    int t = threadIdx.x;
    int img = blockIdx.y;
    int wv = t >> 6, l = t & 63;
    int lo = l & 15, hi = l >> 4;
    const unsigned short* Q = Qall + (size_t)img * SEQ * DIM;
    int row0 = blockIdx.x * 384 + wv * 48;

    // --- load A fragments: 3 m-tiles x 12 k-tiles, once, from L2 ---
    v8s A[3][12];
    #pragma unroll
    for (int mm = 0; mm < 3; ++mm) {
        #pragma unroll
        for (int kk = 0; kk < 12; ++kk) {
            int gr = row0 + mm * 16 + lo;
            v8s z = {0, 0, 0, 0, 0, 0, 0, 0};
            A[mm][kk] = (gr < LSUP)
                ? *(const v8s*)(Kb + (size_t)gr * DIM + kk * 32 + hi * 8)
                : z;
        }
    }

    float srow[3][4];
    #pragma unroll
    for (int mm = 0; mm < 3; ++mm)
        #pragma unroll
        for (int j = 0; j < 4; ++j) srow[mm][j] = 0.f;

    for (int pass = 0; pass < 3; ++pass) {
        int qbase = pass * QTILE;
        int ntiles = (pass < 2) ? 5 : 3;
        int nstage = (pass < 2) ? QTILE : 48;
        // stage B tile
        for (int i = t; i < nstage * 48; i += 512) {
            int qs = i / 48, kc = i % 48;
            int gq = qbase + qs;
            float4 vv = make_float4(0.f, 0.f, 0.f, 0.f);
            if (gq < SEQ) vv = *(const float4*)(Q + (size_t)gq * DIM + kc * 8);
            *(float4*)(Bs + qs * LDB + kc * 8) = vv;
        }
        __syncthreads();

        for (int n = 0; n < ntiles; ++n) {
            v4f acc[3];
            #pragma unroll
            for (int mm = 0; mm < 3; ++mm) acc[mm] = (v4f){0.f, 0.f, 0.f, 0.f};
            const unsigned short* Bn = Bs + (n * 16 + lo) * LDB + hi * 8;
            #pragma unroll
            for (int kk = 0; kk < 12; ++kk) {       // FULL unroll: constant idx
                v8s bb = *(const v8s*)(Bn + kk * 32);
                acc[0] = __builtin_amdgcn_mfma_f32_16x16x32_bf16(A[0][kk], bb, acc[0], 0, 0, 0);
                acc[1] = __builtin_amdgcn_mfma_f32_16x16x32_bf16(A[1][kk], bb, acc[1], 0, 0, 0);
                acc[2] = __builtin_amdgcn_mfma_f32_16x16x32_bf16(A[2][kk], bb, acc[2], 0, 0, 0);
            }
            bool ok = (qbase + n * 16 + lo) < SEQ;
            #pragma unroll
            for (int mm = 0; mm < 3; ++mm)
                #pragma unroll
                for (int j = 0; j < 4; ++j)
                    srow[mm][j] += ok ? __expf(acc[mm][j]) : 0.f;
        }
        __syncthreads();
    }

    // reduce across the 16 column lanes (lo); C/D layout: col=lo, row=hi*4+j
    #pragma unroll
    for (int m = 1; m < 16; m <<= 1)
        #pragma unroll
        for (int mm = 0; mm < 3; ++mm)
            #pragma unroll
            for (int j = 0; j < 4; ++j)
                srow[mm][j] += __shfl_xor(srow[mm][j], m);

    if (lo == 0) {
        #pragma unroll
        for (int mm = 0; mm < 3; ++mm) {
            #pragma unroll
            for (int j = 0; j < 4; ++j) {
                int r = row0 + mm * 16 + hi * 4 + j;
                if (r < LSUP) {
                    float val = srow[mm][j];
                    if (img < NSUP) {
                        if (r / SEQ == img) val = 0.f;        // block-diag mask
                        int w = r / BLOCK_W, rr = r - w * BLOCK_W;
                        Rbf[(size_t)img * (NW * PADW) + w * PADW + rr] = f2bf(val);
                    } else {
                        Rq[(size_t)(img - NSUP) * LSUP + r] = val;
                    }
                }
            }
        }
    }
}

// ---------------------------------------------------------------------------
// Kernel 3: whole 15-step SGD in ONE 640-thread block, R UNPACKED IN REGISTERS.
// launch_bounds(640, 1): only ONE block exists in the grid, so let the
// allocator use up to 512 VGPRs/wave. (Round 5's (640,3) capped VGPRs at 84
// and spilled the R array to scratch -> 358 us of L2-scratch latency.)
// Thread t owns 8 consecutive rows of class w=t>>7 (r0=(t&127)*8); its 25
// R-slices are unpacked ONCE to 200 float VGPRs (pads r>=980 zeroed).
// Per step:  cf from D;  g = sum_b cf[b][w]*R[b];  v -= LR*e*g; e = exp(v/T);
//            D[b][w] = sum e*R  (6-shfl butterfly per b, 2 waves per class).
// Zero memory traffic inside the step loop -> pure VALU on one CU.
// ---------------------------------------------------------------------------
__global__ __launch_bounds__(640, 1) void opt_all(const unsigned short* __restrict__ Rbf,
                                                  const int* __restrict__ labels,
                                                  float* __restrict__ v_out) {
    __shared__ float D_s[128];
    __shared__ float cf_s[128];
    __shared__ float red[10][26];
    __shared__ int lab_s[NSUP];

    int t = threadIdx.x;
    int wave = t >> 6, lane = t & 63;
    int w  = t >> 7;            // class (uniform per wave)
    int r0 = (t & 127) * 8;

    if (t < NSUP) lab_s[t] = labels[t];

    // load + unpack all 25 R-slices into registers, masking pad rows (>= 980)
    float R[NSUP][8];
    #pragma unroll
    for (int b = 0; b < NSUP; ++b) {
        uint4 u = *(const uint4*)(Rbf + (size_t)b * (NW * PADW) + w * PADW + r0);
        R[b][0] = bf2f(u.x & 0xffffu); R[b][1] = bf2f(u.x >> 16);
        R[b][2] = bf2f(u.y & 0xffffu); R[b][3] = bf2f(u.y >> 16);
        R[b][4] = bf2f(u.z & 0xffffu); R[b][5] = bf2f(u.z >> 16);
        R[b][6] = bf2f(u.w & 0xffffu); R[b][7] = bf2f(u.w >> 16);
        #pragma unroll
        for (int j = 0; j < 8; ++j)
            if (r0 + j >= BLOCK_W) R[b][j] = 0.f;
    }

    float v8[8], e8[8];
    #pragma unroll
    for (int j = 0; j < 8; ++j) { v8[j] = 0.f; e8[j] = 1.f; }
    __syncthreads();   // lab_s visible

    // D pass: D[b][w] = sum_r e*R, butterfly within wave, combine 2 waves.
    auto dpass = [&]() {
        #pragma unroll
        for (int b = 0; b < NSUP; ++b) {
            float s = 0.f;
            #pragma unroll
            for (int j = 0; j < 8; ++j) s += e8[j] * R[b][j];
            #pragma unroll
            for (int m = 1; m < 64; m <<= 1) s += __shfl_xor(s, m);
            if (lane == 0) red[wave][b] = s;
        }
        __syncthreads();
        if (t < 125) {
            int b = t / 5, ww = t % 5;
            D_s[t] = red[2 * ww][b] + red[2 * ww + 1][b];
        }
        __syncthreads();
    };

    dpass();    // D_0 (e = 1)

    for (int step = 0; step < OPT_STEPS; ++step) {
        if (t < 125) {
            int b = t / 5, ww = t % 5;
            float Dsum = D_s[b * 5 + 0] + D_s[b * 5 + 1] + D_s[b * 5 + 2]
                       + D_s[b * 5 + 3] + D_s[b * 5 + 4];
            float Dv = D_s[t];
            cf_s[t] = ((Dv / Dsum) - (ww == lab_s[b] ? 1.f : 0.f)) * (INV_T / 25.f) / Dv;
        }
        __syncthreads();

        float g[8];
        #pragma unroll
        for (int j = 0; j < 8; ++j) g[j] = 0.f;
        #pragma unroll
        for (int b = 0; b < NSUP; ++b) {
            float c = cf_s[b * 5 + w];
            #pragma unroll
            for (int j = 0; j < 8; ++j) g[j] += c * R[b][j];
        }
        #pragma unroll
        for (int j = 0; j < 8; ++j) {
            v8[j] -= LR_F * e8[j] * g[j];
            e8[j] = __expf(v8[j] * INV_T);
        }
        __syncthreads();

        if (step < OPT_STEPS - 1) dpass();
    }

    #pragma unroll
    for (int j = 0; j < 8; ++j)
        if (r0 + j < BLOCK_W) v_out[w * BLOCK_W + r0 + j] = v8[j];
}

// ---------------------------------------------------------------------------
// Kernel 4: out[qb][w] = log( sum_{r in w} e^{v/T} * Rq[qb][w*980+r] )
// ---------------------------------------------------------------------------
__global__ __launch_bounds__(256) void final_pred(const float* __restrict__ Rq,
                                                  const float* __restrict__ v,
                                                  float* __restrict__ out) {
    __shared__ float wsum[4];
    int blk = blockIdx.x;           // qb*5 + w
    int qb = blk / 5, w = blk % 5;
    const float* R  = Rq + (size_t)qb * LSUP + w * BLOCK_W;
    const float* vb = v + w * BLOCK_W;
    int t = threadIdx.x;
    float p = 0.f;
    for (int i = t; i < BLOCK_W; i += 256) p += __expf(vb[i] * INV_T) * R[i];
    #pragma unroll
    for (int off = 32; off; off >>= 1) p += __shfl_down(p, off);
    if ((t & 63) == 0) wsum[t >> 6] = p;
    __syncthreads();
    if (t == 0) out[blk] = logf(wsum[0] + wsum[1] + wsum[2] + wsum[3]);
}

// ---------------------------------------------------------------------------
extern "C" void kernel_launch(void* const* d_in, const int* in_sizes, int n_in,
                              void* d_out, int out_size, void* d_ws, size_t ws_size,
                              hipStream_t stream) {
    const float* sup_key = (const float*)d_in[0];   // [25,196,384]
    const float* sup_qry = (const float*)d_in[1];   // [25,196,384]
    const float* qry     = (const float*)d_in[2];   // [75,196,384]
    const int*   labels  = (const int*)d_in[3];     // [25]
    float* out = (float*)d_out;                     // [75,5]

    char* ws = (char*)d_ws;
    size_t off = 0;
    auto take = [&](size_t bytes) {
        char* p = ws + off;
        off = (off + bytes + 255) & ~(size_t)255;
        return p;
    };
    unsigned short* Kb   = (unsigned short*)take((size_t)LSUP * DIM * 2);
    unsigned short* Qall = (unsigned short*)take((size_t)NIMG * SEQ * DIM * 2);
    float*          Rq   = (float*)take((size_t)NQRY * LSUP * 4);
    unsigned short* Rbf  = (unsigned short*)take((size_t)NSUP * NW * PADW * 2);
    float*          v    = (float*)take((size_t)LSUP * 4);

    int nrows = 2 * LSUP + NQRY * SEQ;              // 24500
    norm_all<<<(nrows + 3) / 4, 256, 0, stream>>>(sup_key, sup_qry, qry, Kb, Qall);

    fused_gemm<<<dim3(13, NIMG), 512, 0, stream>>>(Kb, Qall, Rq, Rbf);

    opt_all<<<1, 640, 0, stream>>>(Rbf, labels, v);

    final_pred<<<NQRY * NW, 256, 0, stream>>>(Rq, v, out);
}

// Round 7
// 534.910 us; speedup vs baseline: 1.0818x; 1.0228x over previous
//
#include <hip/hip_runtime.h>
#include <hip/hip_bf16.h>

// ---- problem constants ----
#define NW 5
#define KS 5
#define SEQ 196
#define DIM 384
#define NSUP 25        // NW*KS support images
#define NQRY 75        // query images
#define NIMG 100       // NSUP + NQRY
#define LSUP 4900      // NSUP*SEQ support rows
#define BLOCK_W 980    // KS*SEQ rows per class block
#define PADW 1024      // padded class block for opt kernel
#define OPT_STEPS 15

static constexpr float TEMP_F = 0.0510310363f;
static constexpr float INV_T  = 1.0f / TEMP_F;   // ~19.5959
static constexpr float LR_F   = 0.1f;

typedef short v8s __attribute__((ext_vector_type(8)));   // 8 x bf16 frag (4 VGPRs)
typedef float v4f __attribute__((ext_vector_type(4)));   // 4 x f32 acc

__device__ inline unsigned short f2bf(float x) {
    unsigned int u = __float_as_uint(x);
    u += 0x7fffu + ((u >> 16) & 1u);
    return (unsigned short)(u >> 16);
}
__device__ inline float bfLO(unsigned int u) {           // low bf16 -> f32
    return __uint_as_float(u << 16);
}
__device__ inline float bfHI(unsigned int u) {           // high bf16 -> f32
    return __uint_as_float(u & 0xffff0000u);
}

// ---------------------------------------------------------------------------
// Kernel 1: fused normalize of all 24500 rows -> bf16. One wave per row.
// rows [0,4900): sup_key -> Kb (pre-scaled by 1/T)
// rows [4900,9800): sup_qry -> Qall[0..4899]
// rows [9800,24500): qry -> Qall[4900..19599]
// ---------------------------------------------------------------------------
__global__ __launch_bounds__(256) void norm_all(const float* __restrict__ sup_key,
                                                const float* __restrict__ sup_qry,
                                                const float* __restrict__ qry,
                                                unsigned short* __restrict__ Kb,
                                                unsigned short* __restrict__ Qall) {
    int row = blockIdx.x * 4 + (threadIdx.x >> 6);
    int lane = threadIdx.x & 63;
    if (row >= 2 * LSUP + NQRY * SEQ) return;
    const float* src;
    unsigned short* dst;
    float scale;
    if (row < LSUP) {
        src = sup_key + (size_t)row * DIM;
        dst = Kb + (size_t)row * DIM;
        scale = INV_T;
    } else if (row < 2 * LSUP) {
        src = sup_qry + (size_t)(row - LSUP) * DIM;
        dst = Qall + (size_t)(row - LSUP) * DIM;
        scale = 1.0f;
    } else {
        src = qry + (size_t)(row - 2 * LSUP) * DIM;
        dst = Qall + (size_t)(row - LSUP) * DIM;
        scale = 1.0f;
    }
    float x[6];
    float s = 0.f;
    #pragma unroll
    for (int i = 0; i < 6; ++i) { x[i] = src[lane + 64 * i]; s += x[i] * x[i]; }
    #pragma unroll
    for (int m = 1; m < 64; m <<= 1) s += __shfl_xor(s, m);
    float sc = scale / fmaxf(sqrtf(s), 1e-8f);
    #pragma unroll
    for (int i = 0; i < 6; ++i) dst[lane + 64 * i] = f2bf(x[i] * sc);
}

// ---------------------------------------------------------------------------
// Kernel 2: MFMA fused exp-sum GEMM, A-in-registers / full-image-B-in-LDS.
//   R[img][r] = sum_qs exp( (Kn[r] . Qimg[qs]) / T )    (K pre-scaled by 1/T)
// Block: 512 thr = 8 waves, each wave owns 48 rows (3 m-tiles), full K=384
// held in registers (36 v8s frags -> 144 VGPRs; ALL indexing constant so the
// array stays in registers). B staged in 3 col-passes of 80 qs.
// img<25 -> write bf16 to Rbf[b][w*1024+r] (masked rows -> 0)
// img>=25 -> write f32 to Rq[(img-25)*4900 + r]
// ---------------------------------------------------------------------------
#define QTILE 80
#define LDB   392   // LDS row stride in shorts (384+8): 16B aligned

__global__ __launch_bounds__(512, 2) void fused_gemm(
    const unsigned short* __restrict__ Kb,
    const unsigned short* __restrict__ Qall,
    float* __restrict__ Rq,
    unsigned short* __restrict__ Rbf)
{
    __shared__ __align__(16) unsigned short Bs[QTILE * LDB];  // 62720 B

    int t = threadIdx.x;
    int img = blockIdx.y;
    int wv = t >> 6, l = t & 63;
    int lo = l & 15, hi = l >> 4;
    const unsigned short* Q = Qall + (size_t)img * SEQ * DIM;
    int row0 = blockIdx.x * 384 + wv * 48;

    // --- load A fragments: 3 m-tiles x 12 k-tiles, once, from L2 ---
    v8s A[3][12];
    #pragma unroll
    for (int mm = 0; mm < 3; ++mm) {
        #pragma unroll
        for (int kk = 0; kk < 12; ++kk) {
            int gr = row0 + mm * 16 + lo;
            v8s z = {0, 0, 0, 0, 0, 0, 0, 0};
            A[mm][kk] = (gr < LSUP)
                ? *(const v8s*)(Kb + (size_t)gr * DIM + kk * 32 + hi * 8)
                : z;
        }
    }

    float srow[3][4];
    #pragma unroll
    for (int mm = 0; mm < 3; ++mm)
        #pragma unroll
        for (int j = 0; j < 4; ++j) srow[mm][j] = 0.f;

    for (int pass = 0; pass < 3; ++pass) {
        int qbase = pass * QTILE;
        int ntiles = (pass < 2) ? 5 : 3;
        int nstage = (pass < 2) ? QTILE : 48;
        // stage B tile
        for (int i = t; i < nstage * 48; i += 512) {
            int qs = i / 48, kc = i % 48;
            int gq = qbase + qs;
            float4 vv = make_float4(0.f, 0.f, 0.f, 0.f);
            if (gq < SEQ) vv = *(const float4*)(Q + (size_t)gq * DIM + kc * 8);
            *(float4*)(Bs + qs * LDB + kc * 8) = vv;
        }
        __syncthreads();

        for (int n = 0; n < ntiles; ++n) {
            v4f acc[3];
            #pragma unroll
            for (int mm = 0; mm < 3; ++mm) acc[mm] = (v4f){0.f, 0.f, 0.f, 0.f};
            const unsigned short* Bn = Bs + (n * 16 + lo) * LDB + hi * 8;
            #pragma unroll
            for (int kk = 0; kk < 12; ++kk) {       // FULL unroll: constant idx
                v8s bb = *(const v8s*)(Bn + kk * 32);
                acc[0] = __builtin_amdgcn_mfma_f32_16x16x32_bf16(A[0][kk], bb, acc[0], 0, 0, 0);
                acc[1] = __builtin_amdgcn_mfma_f32_16x16x32_bf16(A[1][kk], bb, acc[1], 0, 0, 0);
                acc[2] = __builtin_amdgcn_mfma_f32_16x16x32_bf16(A[2][kk], bb, acc[2], 0, 0, 0);
            }
            bool ok = (qbase + n * 16 + lo) < SEQ;
            #pragma unroll
            for (int mm = 0; mm < 3; ++mm)
                #pragma unroll
                for (int j = 0; j < 4; ++j)
                    srow[mm][j] += ok ? __expf(acc[mm][j]) : 0.f;
        }
        __syncthreads();
    }

    // reduce across the 16 column lanes (lo); C/D layout: col=lo, row=hi*4+j
    #pragma unroll
    for (int m = 1; m < 16; m <<= 1)
        #pragma unroll
        for (int mm = 0; mm < 3; ++mm)
            #pragma unroll
            for (int j = 0; j < 4; ++j)
                srow[mm][j] += __shfl_xor(srow[mm][j], m);

    if (lo == 0) {
        #pragma unroll
        for (int mm = 0; mm < 3; ++mm) {
            #pragma unroll
            for (int j = 0; j < 4; ++j) {
                int r = row0 + mm * 16 + hi * 4 + j;
                if (r < LSUP) {
                    float val = srow[mm][j];
                    if (img < NSUP) {
                        if (r / SEQ == img) val = 0.f;        // block-diag mask
                        int w = r / BLOCK_W, rr = r - w * BLOCK_W;
                        Rbf[(size_t)img * (NW * PADW) + w * PADW + rr] = f2bf(val);
                    } else {
                        Rq[(size_t)(img - NSUP) * LSUP + r] = val;
                    }
                }
            }
        }
    }
}

// ---------------------------------------------------------------------------
// Kernel 3: whole 15-step SGD in ONE 640-thread block, R PACKED in registers.
// Constraint discovered R5/R6: 640 thr = 10 waves -> 3 waves/SIMD -> hard cap
// ~170 VGPR/wave. So R is kept PACKED (25 x uint4 = 100 VGPRs; total live
// ~145 < 170) and unpacked on the fly (1 VALU op per bf16). The empty
// asm volatile "+v" pins redefine the loaded values so the compiler can
// neither sink nor rematerialize the global loads (R6's failure mode:
// reload-from-L2 every pass, 25 serial loads x 31 passes).
// Per step: cf (LDS) -> grad g=sum_b cf*R -> v,e update -> D=sum_r e*R
// (butterfly + 2-wave combine). Zero memory traffic in the loop.
// ---------------------------------------------------------------------------
__global__ __launch_bounds__(640, 1) void opt_all(const unsigned short* __restrict__ Rbf,
                                                  const int* __restrict__ labels,
                                                  float* __restrict__ v_out) {
    __shared__ float D_s[128];
    __shared__ float cf_s[128];
    __shared__ float red[10][32];
    __shared__ int lab_s[NSUP];

    int t = threadIdx.x;
    int wave = t >> 6, lane = t & 63;
    int w  = t >> 7;            // class (uniform per wave)
    int r0 = (t & 127) * 8;

    if (t < NSUP) lab_s[t] = labels[t];

    // one-time load of this thread's 25 R-slices (packed bf16 x8 = uint4)
    const unsigned short* Rbase = Rbf + w * PADW + r0;
    uint4 Rp[NSUP];
    #pragma unroll
    for (int b = 0; b < NSUP; ++b)
        Rp[b] = *(const uint4*)(Rbase + (size_t)b * (NW * PADW));
    // zero pad rows (>= 980; Rbf pads hold poison) and PIN into VGPRs
    #pragma unroll
    for (int b = 0; b < NSUP; ++b) {
        if (r0 >= BLOCK_W)          { Rp[b].x = 0; Rp[b].y = 0; Rp[b].z = 0; Rp[b].w = 0; }
        else if (r0 + 4 >= BLOCK_W) { Rp[b].z = 0; Rp[b].w = 0; }
        asm volatile("" : "+v"(Rp[b].x), "+v"(Rp[b].y), "+v"(Rp[b].z), "+v"(Rp[b].w));
    }

    float v8[8], e8[8];
    #pragma unroll
    for (int j = 0; j < 8; ++j) { v8[j] = 0.f; e8[j] = 1.f; }
    __syncthreads();   // lab_s visible

    // D pass: D[b][w] = sum_r e*R, butterfly within wave, combine 2 waves.
    auto dpass = [&]() {
        #pragma unroll
        for (int b = 0; b < NSUP; ++b) {
            float s = e8[0] * bfLO(Rp[b].x) + e8[1] * bfHI(Rp[b].x)
                    + e8[2] * bfLO(Rp[b].y) + e8[3] * bfHI(Rp[b].y)
                    + e8[4] * bfLO(Rp[b].z) + e8[5] * bfHI(Rp[b].z)
                    + e8[6] * bfLO(Rp[b].w) + e8[7] * bfHI(Rp[b].w);
            #pragma unroll
            for (int m = 1; m < 64; m <<= 1) s += __shfl_xor(s, m);
            if (lane == 0) red[wave][b] = s;
        }
        __syncthreads();
        if (t < 125) {
            int b = t / 5, ww = t % 5;
            D_s[t] = red[2 * ww][b] + red[2 * ww + 1][b];
        }
        __syncthreads();
    };

    dpass();    // D_0 (e = 1)

    for (int step = 0; step < OPT_STEPS; ++step) {
        if (t < 125) {
            int b = t / 5, ww = t % 5;
            float Dsum = D_s[b * 5 + 0] + D_s[b * 5 + 1] + D_s[b * 5 + 2]
                       + D_s[b * 5 + 3] + D_s[b * 5 + 4];
            float Dv = D_s[t];
            cf_s[t] = ((Dv / Dsum) - (ww == lab_s[b] ? 1.f : 0.f)) * (INV_T / 25.f) / Dv;
        }
        __syncthreads();

        float g[8];
        #pragma unroll
        for (int j = 0; j < 8; ++j) g[j] = 0.f;
        #pragma unroll
        for (int b = 0; b < NSUP; ++b) {
            float c = cf_s[b * 5 + w];
            g[0] += c * bfLO(Rp[b].x); g[1] += c * bfHI(Rp[b].x);
            g[2] += c * bfLO(Rp[b].y); g[3] += c * bfHI(Rp[b].y);
            g[4] += c * bfLO(Rp[b].z); g[5] += c * bfHI(Rp[b].z);
            g[6] += c * bfLO(Rp[b].w); g[7] += c * bfHI(Rp[b].w);
        }
        #pragma unroll
        for (int j = 0; j < 8; ++j) {
            v8[j] -= LR_F * e8[j] * g[j];
            e8[j] = __expf(v8[j] * INV_T);
        }

        if (step < OPT_STEPS - 1) dpass();   // has its own barriers
    }

    #pragma unroll
    for (int j = 0; j < 8; ++j)
        if (r0 + j < BLOCK_W) v_out[w * BLOCK_W + r0 + j] = v8[j];
}

// ---------------------------------------------------------------------------
// Kernel 4: out[qb][w] = log( sum_{r in w} e^{v/T} * Rq[qb][w*980+r] )
// ---------------------------------------------------------------------------
__global__ __launch_bounds__(256) void final_pred(const float* __restrict__ Rq,
                                                  const float* __restrict__ v,
                                                  float* __restrict__ out) {
    __shared__ float wsum[4];
    int blk = blockIdx.x;           // qb*5 + w
    int qb = blk / 5, w = blk % 5;
    const float* R  = Rq + (size_t)qb * LSUP + w * BLOCK_W;
    const float* vb = v + w * BLOCK_W;
    int t = threadIdx.x;
    float p = 0.f;
    for (int i = t; i < BLOCK_W; i += 256) p += __expf(vb[i] * INV_T) * R[i];
    #pragma unroll
    for (int off = 32; off; off >>= 1) p += __shfl_down(p, off);
    if ((t & 63) == 0) wsum[t >> 6] = p;
    __syncthreads();
    if (t == 0) out[blk] = logf(wsum[0] + wsum[1] + wsum[2] + wsum[3]);
}

// ---------------------------------------------------------------------------
extern "C" void kernel_launch(void* const* d_in, const int* in_sizes, int n_in,
                              void* d_out, int out_size, void* d_ws, size_t ws_size,
                              hipStream_t stream) {
    const float* sup_key = (const float*)d_in[0];   // [25,196,384]
    const float* sup_qry = (const float*)d_in[1];   // [25,196,384]
    const float* qry     = (const float*)d_in[2];   // [75,196,384]
    const int*   labels  = (const int*)d_in[3];     // [25]
    float* out = (float*)d_out;                     // [75,5]

    char* ws = (char*)d_ws;
    size_t off = 0;
    auto take = [&](size_t bytes) {
        char* p = ws + off;
        off = (off + bytes + 255) & ~(size_t)255;
        return p;
    };
    unsigned short* Kb   = (unsigned short*)take((size_t)LSUP * DIM * 2);
    unsigned short* Qall = (unsigned short*)take((size_t)NIMG * SEQ * DIM * 2);
    float*          Rq   = (float*)take((size_t)NQRY * LSUP * 4);
    unsigned short* Rbf  = (unsigned short*)take((size_t)NSUP * NW * PADW * 2);
    float*          v    = (float*)take((size_t)LSUP * 4);

    int nrows = 2 * LSUP + NQRY * SEQ;              // 24500
    norm_all<<<(nrows + 3) / 4, 256, 0, stream>>>(sup_key, sup_qry, qry, Kb, Qall);

    fused_gemm<<<dim3(13, NIMG), 512, 0, stream>>>(Kb, Qall, Rq, Rbf);

    opt_all<<<1, 640, 0, stream>>>(Rbf, labels, v);

    final_pred<<<NQRY * NW, 256, 0, stream>>>(Rq, v, out);
}